// Round 5
// baseline (1623.983 us; speedup 1.0000x reference)
//
#include <hip/hip_runtime.h>

// Q4_0 quantized linear: out[16, 11008] = x[16, 4096] @ ((w_q-8)*w_scale).T + bias
// All fp32; w_q holds int32 nibble values in [0,16).
//
// R5: direct-to-LDS staging rewrite.
// Key insight: each weight row is consumed by exactly ONE thread -- the LDS
// w-tile has no cross-thread reuse, it is purely a coalescing reshaper. So:
//  - stage RAW int32 via __builtin_amdgcn_global_load_lds (16 B/lane, 1 KB
//    per wave-instr, 8 instrs fire-and-forget per sub): no staging VGPRs
//    (kills the R1/R2/R3 register-allocator failures at the root), no pack
//    VALU, and ~16 KB in flight per wave (Little's law satisfied; the old
//    unroll-4 reg staging had 4 KB and was the ~5x latency stall).
//  - R=1: thread t owns row t. acc[16] + temps ~= 55 VGPR.
//  - LDS = xs 8 KiB + ws 32 KiB = 40 KiB -> exactly 4 blocks/CU.
//    Grid 43 x 32 = 1376 blocks = 5.4/CU; 16 waves/CU resident.
//  - ws is row-major [256][32] int (row = 128 B = 32 banks), so the per-row
//    ds_read_b128 would be a 32-way conflict. Fix: XOR-swizzle the 16-B
//    chunk index with (row&7). global_load_lds writes LDS linearly, so the
//    swizzle is applied on the PER-LANE GLOBAL source address (legal: the
//    global side is per-lane; rule: both-sides-or-neither) and mirrored on
//    the ds_read. Reaches the structural floor (8 accesses/bank).
// History: R0 110us (4-deep staging, latency-bound); R1/R2/R3 register
// blowups from reg-staged prefetch variants; R4 ~105us (2x blocks, no gain
// -> stall is pipeline depth, not occupancy).

constexpr int T       = 16;
constexpr int IN      = 4096;
constexpr int OUT     = 11008;
constexpr int NSCALE  = IN / 32;        // 128 scales per row
constexpr int THREADS = 256;
constexpr int ROWSB   = THREADS;        // 1 row per thread; 11008 = 43*256 exact
constexpr int CK      = 128;            // k per block -> 32 k-splits (as R0)
constexpr int WSUB    = 32;             // k per stage (== Q4_0 block size)
constexpr int NSUB    = CK / WSUB;      // 4
constexpr int XPAD    = 16;             // xs row stride floats (64 B)

__device__ __forceinline__ void gload_lds16(const int* g, int* l) {
    // 16 B per lane, global (per-lane addr) -> LDS (wave-uniform base + lane*16)
    __builtin_amdgcn_global_load_lds(
        (const __attribute__((address_space(1))) void*)g,
        (__attribute__((address_space(3))) void*)l,
        16, 0, 0);
}

__global__ __launch_bounds__(THREADS, 4) void qlinear_dlds(
    const float* __restrict__ x,        // [T, IN]
    const int*   __restrict__ w_q,      // [OUT, IN]
    const float* __restrict__ w_scale,  // [OUT, NSCALE]
    const float* __restrict__ bias,     // [OUT]
    float* __restrict__ out)            // [T, OUT] (pre-zeroed)
{
    __shared__ __align__(16) float xs[CK][XPAD];      // 8 KiB
    __shared__ __align__(16) int   ws[ROWSB * WSUB];  // 32 KiB raw int32 weights

    const int tid  = threadIdx.x;
    const int row0 = blockIdx.x * ROWSB;
    const int k0   = blockIdx.y * CK;
    const int row  = row0 + tid;        // < OUT always (exact tiling)

    // ---- stage x chunk transposed: xs[k][t] = x[t][k0+k] (coalesced) ----
    #pragma unroll
    for (int it = 0; it < CK * T / THREADS; ++it) {  // 8
        int idx = it * THREADS + tid;
        int t   = idx >> 7;          // idx / CK
        int k   = idx & (CK - 1);
        xs[k][t] = x[t * IN + k0 + k];
    }

    // ---- per-row scales for the 4 sub-blocks of this k-chunk ----
    const float4 sc = *(const float4*)(w_scale + row * NSCALE + (k0 >> 5));

    // ---- staging geometry ----
    // One wave-instr moves 8 rows x 128 B. lane l: r8 = l>>3 (row within
    // group), c = l&7 (16-B slot). Slot (r8,c) receives global chunk c^r8,
    // so reading row r chunk j uses LDS chunk j^(r&7)  (r8 == row&7 since
    // groups are 8-aligned).
    const int lane_r8 = (tid >> 3) & 7;
    const int lane_c  = tid & 7;
    const int phys_c  = lane_c ^ lane_r8;   // swizzled global chunk index
    const int wrow0   = tid & ~63;          // wave's first row in the block

    auto stage_w = [&](int s) {
        #pragma unroll
        for (int i = 0; i < 8; ++i) {       // 8 x 1 KB per wave, fire-and-forget
            const int  r = wrow0 + i * 8 + lane_r8;
            const int* g = w_q + (size_t)(row0 + r) * IN + (k0 + s * WSUB + phys_c * 4);
            int*       l = ws + (wrow0 + i * 8) * WSUB;   // wave-uniform base
            gload_lds16(g, l);
        }
    };

    float acc[T];
    #pragma unroll
    for (int t = 0; t < T; ++t) acc[t] = 0.0f;

    stage_w(0);
    __syncthreads();    // drains lgkm (xs writes) + vmcnt (ws sub-0 loads)

    #pragma unroll
    for (int sub = 0; sub < NSUB; ++sub) {           // 4
        const float s  = (sub == 0) ? sc.x : (sub == 1) ? sc.y
                       : (sub == 2) ? sc.z : sc.w;   // sub is constant
        const float s8 = -8.0f * s;                  // exact

        for (int k4 = 0; k4 < WSUB / 4; ++k4) {      // 8 (rolled)
            // own row, swizzled chunk: structural-minimum bank spread
            const int4 qv = *(const int4*)(ws + tid * WSUB + ((k4 ^ (tid & 7)) << 2));

            #pragma unroll
            for (int kk = 0; kk < 4; ++kk) {
                const int qq = (kk == 0) ? qv.x : (kk == 1) ? qv.y
                             : (kk == 2) ? qv.z : qv.w;
                // (q - 8) * s with a single rounding; v_cvt_f32_i32 + fma
                const float wv = fmaf((float)qq, s, s8);
                const float4* xp = (const float4*)&xs[sub * WSUB + k4 * 4 + kk][0];
                const float4 x0 = xp[0], x1 = xp[1], x2 = xp[2], x3 = xp[3];
                acc[0]  = fmaf(wv, x0.x, acc[0]);
                acc[1]  = fmaf(wv, x0.y, acc[1]);
                acc[2]  = fmaf(wv, x0.z, acc[2]);
                acc[3]  = fmaf(wv, x0.w, acc[3]);
                acc[4]  = fmaf(wv, x1.x, acc[4]);
                acc[5]  = fmaf(wv, x1.y, acc[5]);
                acc[6]  = fmaf(wv, x1.z, acc[6]);
                acc[7]  = fmaf(wv, x1.w, acc[7]);
                acc[8]  = fmaf(wv, x2.x, acc[8]);
                acc[9]  = fmaf(wv, x2.y, acc[9]);
                acc[10] = fmaf(wv, x2.z, acc[10]);
                acc[11] = fmaf(wv, x2.w, acc[11]);
                acc[12] = fmaf(wv, x3.x, acc[12]);
                acc[13] = fmaf(wv, x3.y, acc[13]);
                acc[14] = fmaf(wv, x3.z, acc[14]);
                acc[15] = fmaf(wv, x3.w, acc[15]);
            }
        }

        if (sub + 1 < NSUB) {
            __syncthreads();        // all waves done reading ws
            stage_w(sub + 1);
            __syncthreads();        // loads landed (barrier drains vmcnt);
                                    // cross-block overlap (4/CU) hides this
        }
    }

    // ---- epilogue: bias (split 0 only) + atomic combine across splits ----
    const float b = (blockIdx.y == 0) ? bias[row] : 0.0f;
    #pragma unroll
    for (int t = 0; t < T; ++t)
        atomicAdd(out + t * OUT + row, acc[t] + b);
}

extern "C" void kernel_launch(void* const* d_in, const int* in_sizes, int n_in,
                              void* d_out, int out_size, void* d_ws, size_t ws_size,
                              hipStream_t stream) {
    const float* x       = (const float*)d_in[0];
    const int*   w_q     = (const int*)d_in[1];
    const float* w_scale = (const float*)d_in[2];
    const float* bias    = (const float*)d_in[3];
    float*       out     = (float*)d_out;

    // Zero the (0xAA-poisoned) output; captured as a graph memset node.
    hipMemsetAsync(d_out, 0, (size_t)out_size * sizeof(float), stream);

    dim3 grid(OUT / ROWSB, IN / CK);   // 43 x 32 = 1376 blocks
    qlinear_dlds<<<grid, THREADS, 0, stream>>>(x, w_q, w_scale, bias, out);
}